// Round 3
// baseline (864.592 us; speedup 1.0000x reference)
//
#include <hip/hip_runtime.h>

typedef float floatx4 __attribute__((ext_vector_type(4)));
typedef short short8 __attribute__((ext_vector_type(8)));

#define H 768
#define NMENT 4096
#define TOTALP 131072
#define MAXK 64
#define BM 128
#define BN 128
#define BK 64
#define NSPLIT 6
#define LDA_S 72   // shorts per A row in LDS: 64 data + 8 pad

__device__ __forceinline__ unsigned short f32_to_bf16(float f) {
    unsigned int u = __builtin_bit_cast(unsigned int, f);
    u = u + 0x7FFFu + ((u >> 16) & 1u);   // round-to-nearest-even
    return (unsigned short)(u >> 16);
}

__device__ __forceinline__ short8 pack8(float4 a, float4 b) {
    short8 r;
    r[0] = (short)f32_to_bf16(a.x); r[1] = (short)f32_to_bf16(a.y);
    r[2] = (short)f32_to_bf16(a.z); r[3] = (short)f32_to_bf16(a.w);
    r[4] = (short)f32_to_bf16(b.x); r[5] = (short)f32_to_bf16(b.y);
    r[6] = (short)f32_to_bf16(b.z); r[7] = (short)f32_to_bf16(b.w);
    return r;
}

__device__ __forceinline__ void glds16(const unsigned short* g, unsigned short* l) {
    __builtin_amdgcn_global_load_lds(
        (const __attribute__((address_space(1))) unsigned int*)g,
        (__attribute__((address_space(3))) unsigned int*)l, 16, 0, 0);
}

// K0: W1 [1536 x 768] row-major -> BtA[n][k] = W1[k][n] (k<768), BtB[n][k] = W1[768+k][n], bf16
__global__ void k0_transpose(const float* __restrict__ W1,
                             unsigned short* __restrict__ BtA,
                             unsigned short* __restrict__ BtB) {
    __shared__ float tile[32][33];
    const int k0 = blockIdx.x * 32;
    const int n0 = blockIdx.y * 32;
    const int tx = threadIdx.x;
    const int ty = threadIdx.y;
#pragma unroll
    for (int i = 0; i < 4; ++i)
        tile[ty + i * 8][tx] = W1[(k0 + ty + i * 8) * H + n0 + tx];
    __syncthreads();
    unsigned short* dst = (k0 < H) ? BtA : BtB;
    const int kb = (k0 >= H) ? (k0 - H) : k0;
#pragma unroll
    for (int i = 0; i < 4; ++i) {
        const int n = n0 + ty + i * 8;
        dst[n * H + kb + tx] = f32_to_bf16(tile[tx][ty + i * 8]);
    }
}

// K3: out[n][j] = 0.5*faiss[n][j] for j<64, nota for j==64 (b2 added by nsplit==0 k2 blocks)
__global__ void k3_init_out(const float* __restrict__ faiss,
                            const float* __restrict__ nota,
                            float* __restrict__ out) {
    const int i = blockIdx.x * 256 + threadIdx.x;
    if (i < NMENT * (MAXK + 1)) {
        const int n = i / (MAXK + 1);
        const int j = i - n * (MAXK + 1);
        out[i] = (j < MAXK) ? 0.5f * faiss[n * MAXK + j] : nota[0];
    }
}

// Core GEMM, m97 shape: 256 thr / 4 waves, 128x128 tile, BK=64, ~36 KB LDS -> 4 blocks/CU.
// C[t0..t0+127][n0..n0+127] = A(rows fp32 -> bf16) @ Bt^T (bf16 [n][k])
// MODE 0: write M = acc + b1.  MODE 1: h = acc + M[mention]; relu; dot W2; atomicAdd score.
template<int MODE>
__global__ __launch_bounds__(256, 4)
void gemm_core(const float* __restrict__ A, const unsigned short* __restrict__ Bt,
               const float* __restrict__ M, const float* __restrict__ W2,
               const float* __restrict__ b2, const int* __restrict__ mention_idx,
               const int* __restrict__ col_idx, const float* __restrict__ b1,
               float* __restrict__ outp) {
    __shared__ unsigned short ldsA[BM * LDA_S];  // 18432 B
    __shared__ unsigned short ldsB[BN * BK];     // 16384 B, XOR-swizzled 16B chunks
    __shared__ float w2s[BN];
    __shared__ float scoreBuf[BM * 2];

    // XCD grouping: the NSPLIT blocks sharing a t-tile get bids spaced 8 apart
    // (same XCD under bid%8 round-robin) and temporally adjacent -> A stays in that L2.
    const int bid = blockIdx.x;
    const int g = bid / (8 * NSPLIT);
    const int rr = bid % (8 * NSPLIT);
    const int t_tile = g * 8 + (rr & 7);
    const int nsplit = rr >> 3;
    const int t0 = t_tile * BM;
    const int n0 = nsplit * BN;

    const int tid = threadIdx.x;
    const int lane = tid & 63;
    const int w = tid >> 6;           // 4 waves: 2x2 grid of 64x64 wave tiles
    const int wm = w >> 1, wn = w & 1;
    const int l15 = lane & 15, quad = lane >> 4;

    if (tid < BN) w2s[tid] = (MODE == 1) ? W2[n0 + tid] : b1[n0 + tid];

    floatx4 acc[4][4];
#pragma unroll
    for (int mi = 0; mi < 4; ++mi)
#pragma unroll
        for (int ni = 0; ni < 4; ++ni)
            acc[mi][ni] = floatx4{0.f, 0.f, 0.f, 0.f};

    // A staging map: 2 threads per row, 32 floats (128 B) each
    const int arow = tid >> 1;
    const int aseg = tid & 1;
    const float* agp = A + (size_t)(t0 + arow) * H + aseg * 32;
    unsigned short* alp = &ldsA[arow * LDA_S + aseg * 32];

    for (int kc = 0; kc < H; kc += BK) {
        // --- stage A: fp32 -> bf16, padded rows ---
        float4 v0 = *(const float4*)(agp + kc);
        float4 v1 = *(const float4*)(agp + kc + 4);
        float4 v2 = *(const float4*)(agp + kc + 8);
        float4 v3 = *(const float4*)(agp + kc + 12);
        float4 v4 = *(const float4*)(agp + kc + 16);
        float4 v5 = *(const float4*)(agp + kc + 20);
        float4 v6 = *(const float4*)(agp + kc + 24);
        float4 v7 = *(const float4*)(agp + kc + 28);
        *(short8*)(alp)      = pack8(v0, v1);
        *(short8*)(alp + 8)  = pack8(v2, v3);
        *(short8*)(alp + 16) = pack8(v4, v5);
        *(short8*)(alp + 24) = pack8(v6, v7);
        // --- stage B: global_load_lds 16B; slot c holds data chunk c^(row&7) ---
#pragma unroll
        for (int i = 0; i < 4; ++i) {
            const int br = w * 32 + i * 8;          // wave-uniform base row
            const int r = br + (lane >> 3);
            const int cd = (lane & 7) ^ (r & 7);
            glds16(Bt + (size_t)(n0 + r) * H + kc + cd * 8, &ldsB[br * BK]);
        }
        __syncthreads();
        // --- compute: 2 k32 steps, 16 MFMAs each ---
#pragma unroll
        for (int ks = 0; ks < 2; ++ks) {
            short8 a[4], b[4];
#pragma unroll
            for (int mi = 0; mi < 4; ++mi)
                a[mi] = *(const short8*)&ldsA[(wm * 64 + mi * 16 + l15) * LDA_S + ks * 32 + quad * 8];
#pragma unroll
            for (int ni = 0; ni < 4; ++ni) {
                const int nr = wn * 64 + ni * 16 + l15;
                const int slot = (quad + ks * 4) ^ (nr & 7);
                b[ni] = *(const short8*)&ldsB[nr * BK + slot * 8];
            }
#pragma unroll
            for (int mi = 0; mi < 4; ++mi)
#pragma unroll
                for (int ni = 0; ni < 4; ++ni)
                    acc[mi][ni] = __builtin_amdgcn_mfma_f32_16x16x32_bf16(a[mi], b[ni], acc[mi][ni], 0, 0, 0);
        }
        __syncthreads();
    }

    if (MODE == 0) {
#pragma unroll
        for (int ni = 0; ni < 4; ++ni) {
            const int nl = wn * 64 + ni * 16 + l15;
            const float bv = w2s[nl];
#pragma unroll
            for (int mi = 0; mi < 4; ++mi)
#pragma unroll
                for (int r = 0; r < 4; ++r) {
                    const int row = t0 + wm * 64 + mi * 16 + quad * 4 + r;
                    outp[(size_t)row * H + n0 + nl] = acc[mi][ni][r] + bv;
                }
        }
    } else {
#pragma unroll
        for (int mi = 0; mi < 4; ++mi) {
#pragma unroll
            for (int r = 0; r < 4; ++r) {
                const int rl = wm * 64 + mi * 16 + quad * 4 + r;
                const int m = mention_idx[t0 + rl];
                const float* Mrow = M + (size_t)m * H + n0;
                float s = 0.f;
#pragma unroll
                for (int ni = 0; ni < 4; ++ni) {
                    const int nl = wn * 64 + ni * 16 + l15;
                    const float v = acc[mi][ni][r] + Mrow[nl];
                    s = fmaf(fmaxf(v, 0.f), w2s[nl], s);
                }
                s += __shfl_xor(s, 1, 64);
                s += __shfl_xor(s, 2, 64);
                s += __shfl_xor(s, 4, 64);
                s += __shfl_xor(s, 8, 64);
                if (l15 == 0) scoreBuf[rl * 2 + wn] = s;
            }
        }
        __syncthreads();
        if (tid < BM) {
            const int t = t0 + tid;
            float tot = scoreBuf[tid * 2] + scoreBuf[tid * 2 + 1];
            if (nsplit == 0) tot += b2[0];
            atomicAdd(&outp[(size_t)mention_idx[t] * (MAXK + 1) + col_idx[t]], tot);
        }
    }
}

extern "C" void kernel_launch(void* const* d_in, const int* in_sizes, int n_in,
                              void* d_out, int out_size, void* d_ws, size_t ws_size,
                              hipStream_t stream) {
    const float* ment  = (const float*)d_in[0];
    const float* cand  = (const float*)d_in[1];
    const float* W1    = (const float*)d_in[2];
    const float* b1    = (const float*)d_in[3];
    const float* W2    = (const float*)d_in[4];
    const float* b2    = (const float*)d_in[5];
    const float* faiss = (const float*)d_in[6];
    const float* nota  = (const float*)d_in[7];
    const int* mention_idx = (const int*)d_in[8];
    const int* col_idx = (const int*)d_in[9];
    float* out = (float*)d_out;

    // ws: BtA bf16 [768*768] | BtB bf16 [768*768] | M fp32 [4096*768]  (~14.9 MB)
    unsigned short* BtA = (unsigned short*)d_ws;
    unsigned short* BtB = BtA + H * H;
    float* M = (float*)(BtB + H * H);

    k0_transpose<<<dim3(48, 24), dim3(32, 8), 0, stream>>>(W1, BtA, BtB);
    k3_init_out<<<(NMENT * (MAXK + 1) + 255) / 256, 256, 0, stream>>>(faiss, nota, out);
    // K1: M[4096x768] = ment @ W1a + b1 : 32 t-tiles x 6 n-splits = 192 blocks
    gemm_core<0><<<(NMENT / BM) * NSPLIT, 256, 0, stream>>>(
        ment, BtA, nullptr, nullptr, nullptr, nullptr, nullptr, b1, M);
    // K2: 1024 t-tiles x 6 n-splits = 6144 blocks, XCD-grouped
    gemm_core<1><<<(TOTALP / BM) * NSPLIT, 256, 0, stream>>>(
        cand, BtB, M, W2, b2, mention_idx, col_idx, nullptr, out);
}